// Round 11
// baseline (835.591 us; speedup 1.0000x reference)
//
#include <hip/hip_runtime.h>

// InductionNetwork capsule routing, C=256, K=64, H=1024, 3 iterations.
// R18: ONE fused kernel, 256 blocks x 1024 thr, panel-level flag sync.
// R17 post-mortem: flags+co-residency PROVEN correct (passed), but
// __launch_bounds__(1024,8) forced VGPR=32 -> 35MB scratch spills per
// dispatch -> 200us/dispatch. R13 (no spills, WRITE~30MB) showed grid
// RENDEZVOUS costs ~33us each. Never-tested combination = this round:
// flag sync + healthy (1024,4) codegen + grid <= capacity.
// Deadlock safety: grid 256 <= capacity under ALL codegen outcomes
// (VGPR>64 -> 1 blk/CU = 256; VGPR<=64 -> 512; LDS 68.6KB -> 2/CU), so
// every block is resident before any spin -> placement-order-independent.
// Phases per block b (ti=b>>4, tj=b&15):
//   P1 convWt tile (ti,tj) -> Wt row-panel tj     pub wtcnt[tj] (tgt 16)
//   P2 routing0 capsule b -> s                    pub s0c[b>>6] (tgt 64)
//   P3 Q tile (ti,tj) = Wt Wt^T (waits wtcnt)     pub qr[ti], qc[tj] (16)
//   P4 b<128: gemm_y0 (waits s0c[mt],qr[nt]) -> y pub y0c[mt] (tgt 32)
//      b>=128: convWb rows (waits qr[p],qc[p]: Wt panel p consumed)
//                                                 pub wbcnt[p] (tgt 8)
//   P5 routing1 (waits y0c[b>>6]) -> s            pub s1c[b>>6]
//   P6 b<128: gemm_y1 (waits s1c[mt]) -> y        pub y1c[mt]
//   P7 routing2 (waits y1c[b>>6]) -> s            pub s2c[b>>6]
//   P8 b<128: gemm_chat (waits s2c[mt],wbcnt[nt]) pub ccnt[mt]
//   P9 squash (waits ccnt[b>>6]) -> out
// Race-safety: routing_i publishes s_ic AFTER reading y (so gemm may
// overwrite y panel once s_ic[mt]==64); gemm publishes y_ic after reading
// s (so routing may overwrite s once y_ic==32); convWb overwrites Wt
// panel p only after all 31 Q tiles touching p published (qr[p]+qc[p]).
// Split-bf16 operands (verified R6-R17, absmax 4.88e-4):
//   D = Ah.Bh + Ah.Bl + Al.Bh with hi=bf16(x), lo=bf16(x-hi).
// Fallback: R3's proven monolithic kernel if ws too small.

using f32x4  = __attribute__((ext_vector_type(4))) float;
using f32x2  = __attribute__((ext_vector_type(2))) float;
using bf16x8 = __attribute__((ext_vector_type(8))) __bf16;
using bf16x4 = __attribute__((ext_vector_type(4))) __bf16;

struct BfPair { __bf16 hi, lo; };
__device__ inline BfPair split_bf16(float x) {
    BfPair p;
    p.hi = (__bf16)x;
    p.lo = (__bf16)(x - (float)p.hi);
    return p;
}

// ---------------- LDS shapes ------------------------------------------------
struct RoutSM {
    float spart[16][1024];  // 64 KB: per-wave partial s
    float u_s[1024];        //  4 KB: y staged for the dots
    float b_s[64], d_s[64], red_s[16], scale_s;
};
struct QSmem {
    __bf16 a_hi[64 * 64];
    __bf16 a_lo[64 * 64];
    __bf16 b_hi[64 * 64];
    __bf16 b_lo[64 * 64];
};

// ---------------- flag sync (protocol proven R13/R17) -----------------------
__device__ inline unsigned aload(const unsigned* f) {
    return __hip_atomic_load(f, __ATOMIC_ACQUIRE, __HIP_MEMORY_SCOPE_AGENT);
}
__device__ inline void pub1(unsigned* f) {
    __syncthreads();                    // all waves' stores drained to L2
    if (threadIdx.x == 0) {
        __threadfence();                // L2 writeback -> device visible
        __hip_atomic_fetch_add(f, 1u, __ATOMIC_ACQ_REL,
                               __HIP_MEMORY_SCOPE_AGENT);
    }
}
__device__ inline void pub2(unsigned* f1, unsigned* f2) {
    __syncthreads();
    if (threadIdx.x == 0) {
        __threadfence();
        __hip_atomic_fetch_add(f1, 1u, __ATOMIC_ACQ_REL,
                               __HIP_MEMORY_SCOPE_AGENT);
        __hip_atomic_fetch_add(f2, 1u, __ATOMIC_ACQ_REL,
                               __HIP_MEMORY_SCOPE_AGENT);
    }
}
__device__ inline void wait1(const unsigned* f, unsigned tgt) {
    if (threadIdx.x == 0)
        while (aload(f) < tgt) __builtin_amdgcn_s_sleep(2);
    __syncthreads();
    __threadfence();                    // acquire: drop stale lines
}
__device__ inline void wait2(const unsigned* f1, unsigned t1,
                             const unsigned* f2, unsigned t2) {
    if (threadIdx.x == 0)
        while (aload(f1) < t1) __builtin_amdgcn_s_sleep(2);
    if (threadIdx.x == 64)              // second wave spins in parallel
        while (aload(f2) < t2) __builtin_amdgcn_s_sleep(2);
    __syncthreads();
    __threadfence();
}

// ---------------- routing body (R12-exact, 186us-proven) --------------------
// Block = capsule c, 16 waves. Wave w owns enc rows w*4..w*4+3; lane holds
// 16 floats/row. MODE 0: d uniform. MODE 1: b = scale*(E.y). MODE 2: +=.
template <int MODE>
__device__ __forceinline__ void routing_body(
    int c, const float* __restrict__ enc, const float* __restrict__ y0,
    const float* __restrict__ y1, float* __restrict__ bglob,
    __bf16* __restrict__ s_hi, __bf16* __restrict__ s_lo, RoutSM* sm)
{
    const int t = threadIdx.x, lane = t & 63, w = t >> 6;   // 16 waves
    const float* E = enc + (size_t)c * 65536;

    // small prologue loads first so their waitcnt doesn't drain er loads
    float yv = 0.f, sv = 0.f;
    if (MODE > 0) {
        const size_t o = (size_t)c * 1024 + t;
        yv = y0[o] + y1[o];                       // y = Q s (full K)
        sv = (float)s_hi[o] + (float)s_lo[o];     // s as the gemm saw it
    }

    f32x4 er[4][4];                     // enc tile
    #pragma unroll
    for (int r = 0; r < 4; ++r) {
        const float* ek = E + (size_t)(w * 4 + r) * 1024 + lane * 8;
        er[r][0] = *(const f32x4*)(ek);
        er[r][1] = *(const f32x4*)(ek + 4);
        er[r][2] = *(const f32x4*)(ek + 512);
        er[r][3] = *(const f32x4*)(ek + 516);
    }

    if (MODE > 0) {
        sm->u_s[t] = yv;
        float p = yv * sv;                        // norm = s^T Q s = |W s|^2
        #pragma unroll
        for (int off = 32; off; off >>= 1) p += __shfl_xor(p, off, 64);
        if (lane == 0) sm->red_s[w] = p;
        __syncthreads();
        if (t == 0) {
            float n = 0.f;
            #pragma unroll
            for (int i = 0; i < 16; ++i) n += sm->red_s[i];
            sm->scale_s = n / ((1.f + n) * sqrtf(n) + 1e-30f);
        }
        __syncthreads();
        const float scale = sm->scale_s;
        f32x4 uf[4];
        uf[0] = *(const f32x4*)&sm->u_s[lane * 8];
        uf[1] = *(const f32x4*)&sm->u_s[lane * 8 + 4];
        uf[2] = *(const f32x4*)&sm->u_s[512 + lane * 8];
        uf[3] = *(const f32x4*)&sm->u_s[512 + lane * 8 + 4];
        #pragma unroll
        for (int r = 0; r < 4; ++r) {
            float sum = 0.f;
            #pragma unroll
            for (int q = 0; q < 4; ++q)
                #pragma unroll
                for (int j = 0; j < 4; ++j)
                    sum += er[r][q][j] * uf[q][j];
            #pragma unroll
            for (int off = 32; off; off >>= 1) sum += __shfl_xor(sum, off, 64);
            if (lane == 0) {
                const int k = w * 4 + r;
                const float bv =
                    (MODE == 2 ? bglob[c * 64 + k] : 0.f) + scale * sum;
                bglob[c * 64 + k] = bv;     // persist for next iteration
                sm->b_s[k] = bv;
            }
        }
    }
    __syncthreads();

    if (MODE == 0) {
        if (t < 64) sm->d_s[t] = 1.f / 64.f;
    } else if (t < 64) {
        float bv = sm->b_s[t], m = bv;
        #pragma unroll
        for (int off = 32; off; off >>= 1) m = fmaxf(m, __shfl_xor(m, off, 64));
        const float e = expf(bv - m);
        float smm = e;
        #pragma unroll
        for (int off = 32; off; off >>= 1) smm += __shfl_xor(smm, off, 64);
        sm->d_s[t] = e / smm;
    }
    __syncthreads();

    // per-wave partial s from registers (4 rows each)
    #pragma unroll
    for (int q = 0; q < 4; ++q) {
        f32x4 p = {};
        #pragma unroll
        for (int r = 0; r < 4; ++r) {
            const float dk = sm->d_s[w * 4 + r];
            #pragma unroll
            for (int j = 0; j < 4; ++j) p[j] += dk * er[r][q][j];
        }
        const int h = (q >> 1) * 512 + lane * 8 + (q & 1) * 4;
        *(f32x4*)&sm->spart[w][h] = p;
    }
    __syncthreads();

    // cross-wave reduce: 1 h-element per thread; emit split-bf16 s
    {
        float a = 0.f;
        #pragma unroll
        for (int wv = 0; wv < 16; ++wv) a += sm->spart[wv][t];
        const BfPair p = split_bf16(a);
        s_hi[(size_t)c * 1024 + t] = p.hi;
        s_lo[(size_t)c * 1024 + t] = p.lo;
    }
}

// ---------------- 16-wave 64x64 split-bf16 NT GEMM tile (R13/R17-verified) --
// 16 waves in a 4x4 grid, one 16x16 frag each; BK=64 LDS staging,
// XOR-swizzled 128-B rows. Threads [0,512) stage A rows, [512,1024) B rows.
// WQ=1: write split-bf16 Q; WQ=0: write float C.
__device__ __forceinline__ int swz128(int row, int colbyte) {
    return row * 128 + (colbyte ^ ((row & 7) << 4));
}

template <int WQ>
__device__ __forceinline__ void gemm64_16w(
    const __bf16* __restrict__ Ah, const __bf16* __restrict__ Al,
    const __bf16* __restrict__ Bh, const __bf16* __restrict__ Bl,
    int arow0, int brow0, int kbeg, int kend,
    float* __restrict__ Cc, __bf16* __restrict__ Qh, __bf16* __restrict__ Ql,
    int crow0, int ccol0, QSmem* sm)
{
    const int t = threadIdx.x, lane = t & 63, w = t >> 6;
    const int wr = w >> 2, wc = w & 3;          // 4x4 wave grid
    const int half = t >> 9;                    // 0: stage A, 1: stage B
    const int sr   = (t & 511) >> 3;            // row 0..63
    const int scb  = (t & 7) * 16;              // col byte 0..112
    const __bf16* sh = half ? Bh : Ah;
    const __bf16* sl = half ? Bl : Al;
    const size_t g = (size_t)((half ? brow0 : arow0) + sr) * 1024 + scb / 2;
    char* const p_hi = (char*)(half ? sm->b_hi : sm->a_hi) + swz128(sr, scb);
    char* const p_lo = (char*)(half ? sm->b_lo : sm->a_lo) + swz128(sr, scb);

    f32x4 acc = {};
    for (int k0 = kbeg; k0 < kend; k0 += 64) {
        __syncthreads();                        // prev LDS use done
        *(bf16x8*)p_hi = *(const bf16x8*)(sh + g + k0);
        *(bf16x8*)p_lo = *(const bf16x8*)(sl + g + k0);
        __syncthreads();
        #pragma unroll
        for (int kk = 0; kk < 2; ++kk) {
            const int cb = kk * 64 + (lane >> 4) * 16;
            const int m = wr * 16 + (lane & 15);
            const int n = wc * 16 + (lane & 15);
            const bf16x8 ah = *(const bf16x8*)((char*)sm->a_hi + swz128(m, cb));
            const bf16x8 al = *(const bf16x8*)((char*)sm->a_lo + swz128(m, cb));
            const bf16x8 bh = *(const bf16x8*)((char*)sm->b_hi + swz128(n, cb));
            const bf16x8 bl = *(const bf16x8*)((char*)sm->b_lo + swz128(n, cb));
            acc = __builtin_amdgcn_mfma_f32_16x16x32_bf16(ah, bh, acc, 0, 0, 0);
            acc = __builtin_amdgcn_mfma_f32_16x16x32_bf16(ah, bl, acc, 0, 0, 0);
            acc = __builtin_amdgcn_mfma_f32_16x16x32_bf16(al, bh, acc, 0, 0, 0);
        }
    }
    const int rr = (lane >> 4) * 4, colb = lane & 15;
    #pragma unroll
    for (int r = 0; r < 4; ++r) {
        const size_t idx = (size_t)(crow0 + wr * 16 + rr + r) * 1024 +
                           ccol0 + wc * 16 + colb;
        if (WQ) {
            const BfPair p = split_bf16(acc[r]);
            Qh[idx] = p.hi;
            Ql[idx] = p.lo;
        } else {
            Cc[idx] = acc[r];
        }
    }
}

// ---------------- THE fused kernel ------------------------------------------
__global__ __launch_bounds__(1024, 4) void fused_kernel(
    const float* __restrict__ enc, const float* __restrict__ W,
    float* __restrict__ outp, float* __restrict__ bglob,
    __bf16* __restrict__ s_hi, __bf16* __restrict__ s_lo,
    float* __restrict__ y0, float* __restrict__ y1,
    __bf16* __restrict__ Wx_hi, __bf16* __restrict__ Wx_lo,
    __bf16* __restrict__ Q_hi, __bf16* __restrict__ Q_lo,
    unsigned* __restrict__ flg)
{
    __shared__ union { RoutSM r; QSmem q; float tile[64][65]; } sm;
    const int b = blockIdx.x, t = threadIdx.x;
    const int ti = b >> 4, tj = b & 15;

    // flag layout: 32-B stride per counter to limit line contention
    unsigned* wtcnt = flg;              // [p*8]  tgt 16  (Wt row-panel p)
    unsigned* qr    = flg + 128;        // tgt 16 (Q tiles in row-panel)
    unsigned* qc    = flg + 256;        // tgt 16 (Q tiles in col-panel)
    unsigned* wbcnt = flg + 384;        // tgt 8  (Wb row-panel p)
    unsigned* s0c   = flg + 512;        // tgt 64 (s panel, iter0)
    unsigned* y0c   = flg + 544;        // tgt 32 (y panel, iter0)
    unsigned* s1c   = flg + 576;        // tgt 64
    unsigned* y1c   = flg + 608;        // tgt 32
    unsigned* s2c   = flg + 640;        // tgt 64
    unsigned* ccnt  = flg + 672;        // tgt 32 (chat panel)

    // ---- P1: convWt tile (ti,tj): writes Wt row-panel tj ----
    {
        const int tx = t & 63, tg = t >> 6;
        for (int i = tg; i < 64; i += 16)
            sm.tile[i][tx] = W[(size_t)(ti * 64 + i) * 1024 + tj * 64 + tx];
        __syncthreads();
        for (int i = tg; i < 64; i += 16) {
            const size_t idx = (size_t)(tj * 64 + i) * 1024 + ti * 64 + tx;
            const BfPair p = split_bf16(sm.tile[tx][i]);
            Wx_hi[idx] = p.hi;
            Wx_lo[idx] = p.lo;
        }
    }
    pub1(&wtcnt[tj * 8]);

    // ---- P2: routing0 capsule b ----
    routing_body<0>(b, enc, nullptr, nullptr, bglob, s_hi, s_lo, &sm.r);
    pub1(&s0c[(b >> 6) * 8]);

    // ---- P3: Q tile (ti,tj) = Wt Wt^T ----
    wait2(&wtcnt[ti * 8], 16, &wtcnt[tj * 8], 16);
    gemm64_16w<1>(Wx_hi, Wx_lo, Wx_hi, Wx_lo, ti * 64, tj * 64, 0, 1024,
                  nullptr, Q_hi, Q_lo, ti * 64, tj * 64, &sm.q);
    pub2(&qr[ti * 8], &qc[tj * 8]);

    // ---- P4: gemm_y0 (b<128) / convWb (b>=128) ----
    if (b < 128) {
        const int kh = b & 1, task = b >> 1;
        const int mt = task >> 4, nt = task & 15;
        wait2(&s0c[mt * 8], 64, &qr[nt * 8], 16);
        gemm64_16w<0>(s_hi, s_lo, Q_hi, Q_lo, mt * 64, nt * 64,
                      kh * 512, kh * 512 + 512, kh ? y1 : y0,
                      nullptr, nullptr, mt * 64, nt * 64, &sm.q);
        pub1(&y0c[mt * 8]);
    } else {
        const int bb = b - 128, p = bb >> 3;    // 8 W-rows each; panel p
        wait2(&qr[p * 8], 16, &qc[p * 8], 16);  // all Q readers of Wt panel p
        for (int q = 0; q < 8; ++q) {
            const size_t idx = (size_t)bb * 8192 + (size_t)q * 1024 + t;
            const BfPair pp = split_bf16(W[idx]);
            Wx_hi[idx] = pp.hi;                 // Wb overwrites dead Wt
            Wx_lo[idx] = pp.lo;
        }
        pub1(&wbcnt[p * 8]);
    }

    // ---- P5: routing1 ----
    wait1(&y0c[(b >> 6) * 8], 32);
    routing_body<1>(b, enc, y0, y1, bglob, s_hi, s_lo, &sm.r);
    pub1(&s1c[(b >> 6) * 8]);

    // ---- P6: gemm_y1 ----
    if (b < 128) {
        const int kh = b & 1, task = b >> 1;
        const int mt = task >> 4, nt = task & 15;
        wait1(&s1c[mt * 8], 64);
        gemm64_16w<0>(s_hi, s_lo, Q_hi, Q_lo, mt * 64, nt * 64,
                      kh * 512, kh * 512 + 512, kh ? y1 : y0,
                      nullptr, nullptr, mt * 64, nt * 64, &sm.q);
        pub1(&y1c[mt * 8]);
    }

    // ---- P7: routing2 ----
    wait1(&y1c[(b >> 6) * 8], 32);
    routing_body<2>(b, enc, y0, y1, bglob, s_hi, s_lo, &sm.r);
    pub1(&s2c[(b >> 6) * 8]);

    // ---- P8: gemm_chat (B = Wb in Wx) ----
    if (b < 128) {
        const int kh = b & 1, task = b >> 1;
        const int mt = task >> 4, nt = task & 15;
        wait2(&s2c[mt * 8], 64, &wbcnt[nt * 8], 8);
        gemm64_16w<0>(s_hi, s_lo, Wx_hi, Wx_lo, mt * 64, nt * 64,
                      kh * 512, kh * 512 + 512, kh ? y1 : y0,
                      nullptr, nullptr, mt * 64, nt * 64, &sm.q);
        pub1(&ccnt[mt * 8]);
    }

    // ---- P9: squash row b -> out ----
    wait1(&ccnt[(b >> 6) * 8], 32);
    {
        const int lane = t & 63, w = t >> 6;
        const size_t o = (size_t)b * 1024 + t;
        const float v = y0[o] + y1[o];
        float ss = v * v;
        #pragma unroll
        for (int off = 32; off; off >>= 1) ss += __shfl_xor(ss, off, 64);
        if (lane == 0) sm.r.red_s[w] = ss;
        __syncthreads();
        float norm = 0.f;
        #pragma unroll
        for (int i = 0; i < 16; ++i) norm += sm.r.red_s[i];
        const float scale = norm / ((1.f + norm) * sqrtf(norm) + 1e-30f);
        outp[o] = v * scale;
    }
}

// ---------------- fallback: R3's proven monolithic fp32 kernel --------------
__global__ __launch_bounds__(512) void fallback_kernel(
    const float* __restrict__ enc, const float* __restrict__ W,
    float* __restrict__ outp)
{
    __shared__ float u_s[1024], s_s[1024], c_s[1024], chat_s[1024];
    __shared__ float b_s[64], d_s[64], red_s[8];
    const int t = threadIdx.x, lane = t & 63, w = t >> 6;
    const float* erow = enc + (size_t)blockIdx.x * 65536;

    if (t < 64) b_s[t] = 0.f;
    __syncthreads();

    for (int it = 0; it < 3; ++it) {
        if (it > 0) {
            f32x4 uf[4];
            #pragma unroll
            for (int q = 0; q < 2; ++q) {
                uf[2*q]   = *(const f32x4*)&u_s[q*512 + lane*8];
                uf[2*q+1] = *(const f32x4*)&u_s[q*512 + lane*8 + 4];
            }
            for (int r = 0; r < 8; ++r) {
                const int k = w * 8 + r;
                const float* ek = erow + (size_t)k * 1024;
                float sum = 0.f;
                #pragma unroll
                for (int q = 0; q < 2; ++q) {
                    f32x4 e0 = *(const f32x4*)(ek + q*512 + lane*8);
                    f32x4 e1 = *(const f32x4*)(ek + q*512 + lane*8 + 4);
                    #pragma unroll
                    for (int j = 0; j < 4; ++j) {
                        sum += e0[j] * uf[2*q][j];
                        sum += e1[j] * uf[2*q+1][j];
                    }
                }
                #pragma unroll
                for (int off = 32; off; off >>= 1) sum += __shfl_xor(sum, off, 64);
                if (lane == 0) b_s[k] += sum;
            }
            __syncthreads();
        }
        if (t < 64) {
            float bv = b_s[t], m = bv;
            #pragma unroll
            for (int off = 32; off; off >>= 1) m = fmaxf(m, __shfl_xor(m, off, 64));
            float e = expf(bv - m), sm = e;
            #pragma unroll
            for (int off = 32; off; off >>= 1) sm += __shfl_xor(sm, off, 64);
            d_s[t] = e / sm;
        }
        __syncthreads();
        {
            const int h0 = t * 2;
            float a0 = 0.f, a1 = 0.f;
            for (int k = 0; k < 64; ++k) {
                f32x2 ev = *(const f32x2*)(erow + (size_t)k * 1024 + h0);
                a0 += d_s[k] * ev[0]; a1 += d_s[k] * ev[1];
            }
            s_s[h0] = a0; s_s[h0+1] = a1;
        }
        __syncthreads();
        {
            f32x4 sf[4];
            #pragma unroll
            for (int q = 0; q < 2; ++q) {
                sf[2*q]   = *(const f32x4*)&s_s[q*512 + lane*8];
                sf[2*q+1] = *(const f32x4*)&s_s[q*512 + lane*8 + 4];
            }
            for (int r = 0; r < 128; ++r) {
                const int d = w * 128 + r;
                const float* wr = W + (size_t)d * 1024;
                float sum = 0.f;
                #pragma unroll
                for (int q = 0; q < 2; ++q) {
                    f32x4 w0 = *(const f32x4*)(wr + q*512 + lane*8);
                    f32x4 w1 = *(const f32x4*)(wr + q*512 + lane*8 + 4);
                    #pragma unroll
                    for (int j = 0; j < 4; ++j) {
                        sum += w0[j] * sf[2*q][j];
                        sum += w1[j] * sf[2*q+1][j];
                    }
                }
                #pragma unroll
                for (int off = 32; off; off >>= 1) sum += __shfl_xor(sum, off, 64);
                if (lane == 0) chat_s[d] = sum;
            }
        }
        __syncthreads();
        {
            const int h0 = t * 2;
            float v0 = chat_s[h0], v1 = chat_s[h0+1];
            float ss = v0*v0 + v1*v1;
            #pragma unroll
            for (int off = 32; off; off >>= 1) ss += __shfl_xor(ss, off, 64);
            if (lane == 0) red_s[w] = ss;
            __syncthreads();
            float norm = 0.f;
            #pragma unroll
            for (int i = 0; i < 8; ++i) norm += red_s[i];
            const float scale = norm / ((1.f + norm) * sqrtf(norm) + 1e-30f);
            c_s[h0] = v0 * scale; c_s[h0+1] = v1 * scale;
        }
        __syncthreads();
        if (it < 2) {
            const int h0 = t * 2;
            float uu0 = 0.f, uu1 = 0.f;
            for (int d = 0; d < 1024; ++d) {
                f32x2 wv = *(const f32x2*)(W + (size_t)d * 1024 + h0);
                uu0 += c_s[d] * wv[0]; uu1 += c_s[d] * wv[1];
            }
            u_s[h0] = uu0; u_s[h0+1] = uu1;
        } else {
            const int h0 = t * 2;
            f32x2 ov; ov[0] = c_s[h0]; ov[1] = c_s[h0+1];
            *(f32x2*)(outp + (size_t)blockIdx.x * 1024 + h0) = ov;
        }
        __syncthreads();
    }
}

extern "C" void kernel_launch(void* const* d_in, const int* in_sizes, int n_in,
                              void* d_out, int out_size, void* d_ws, size_t ws_size,
                              hipStream_t stream)
{
    const float* enc = (const float*)d_in[0];   // [256,64,1024] fp32
    const float* W   = (const float*)d_in[1];   // [1024,1024]   fp32
    float* outp = (float*)d_out;                // [256,1024]    fp32
    (void)in_sizes; (void)n_in; (void)out_size;

    // ws layout (11.5 MB + flag words)
    char* ws = (char*)d_ws;
    float*    b     = (float*)   (ws + 0x000000);  //  64 KB [256,64]
    __bf16*   s_hi  = (__bf16*)  (ws + 0x080000);  // 512 KB [256,1024]
    __bf16*   s_lo  = (__bf16*)  (ws + 0x100000);  // 512 KB
    float*    y0    = (float*)   (ws + 0x180000);  //   1 MB (y / chat lo-K)
    float*    y1    = (float*)   (ws + 0x280000);  //   1 MB (y / chat hi-K)
    __bf16*   Wx_hi = (__bf16*)  (ws + 0x380000);  //   2 MB  Wt then Wb
    __bf16*   Wx_lo = (__bf16*)  (ws + 0x580000);  //   2 MB
    __bf16*   Q_hi  = (__bf16*)  (ws + 0x780000);  //   2 MB [1024,1024]
    __bf16*   Q_lo  = (__bf16*)  (ws + 0x980000);  //   2 MB
    unsigned* flg   = (unsigned*)(ws + 0xB80000);  //   4 KB flags

    if (ws_size < 0xB81000) {
        fallback_kernel<<<256, 512, 0, stream>>>(enc, W, outp);
        return;
    }

    // zero the flags (ws is poison-filled by the harness each run)
    hipMemsetAsync(flg, 0, 4096, stream);

    fused_kernel<<<256, 1024, 0, stream>>>(
        enc, W, outp, b, s_hi, s_lo, y0, y1,
        Wx_hi, Wx_lo, Q_hi, Q_lo, flg);
}

// Round 12
// 220.274 us; speedup vs baseline: 3.7934x; 3.7934x over previous
//
#include <hip/hip_runtime.h>

// InductionNetwork capsule routing, C=256, K=64, H=1024, 3 iterations.
// R19: 7-dispatch stream-ordered pipeline, NO intra-kernel sync.
// R13-R18 verdict (5 experiments): any device-scope sync on 8 XCDs
// (rendezvous ~33-40us each; flag storms 770us) loses badly to plain
// dispatch boundaries (~13us). Best verified = R12/R16 8-dispatch 186us.
// R19 removes one boundary ALGEBRAICALLY: the Q-GEMM stages its operands
// directly from W with an on-the-fly transpose (a[m][k] = W[k][col0+m]:
// consecutive lanes m -> consecutive addresses, coalesced 4B/lane loads,
// 8 packed into one swizzled bf16x8 LDS write; identical split_bf16
// values -> bit-identical Q). convert_wt is deleted; convWb (input-only)
// joins dispatch A. Dispatch A = routing0 || Q || convWb, all pure
// input readers -> zero dependencies, zero sync.
//   A: [routing0 256][Q 136 tri tiles from W][convWb 32]   (424 blocks)
//   B: gemm_y0    y = Q s (tiled, split-K x2)
//   C: routing1   norm=s.y -> scale; b = scale*(E.y); s
//   D: gemm_y1    y = Q s
//   E: routing2   b += scale*(E.y); s
//   F: gemm_chat  chat = W s (tiled, B = Wb)
//   G: squash_out out = squash(chat)
// Q symmetric: 136 upper-triangle 64x64 tiles + mirror writes (R16-
// verified). Routing body R12-exact (186us-proven).
// Split-bf16 operands (verified R6-R18, absmax 4.88e-4):
//   D = Ah.Bh + Ah.Bl + Al.Bh with hi=bf16(x), lo=bf16(x-hi).
// Fragment layout verified R4/R6/R7: A[m=lane&15][k=(lane>>4)*8+j];
// C/D col=lane&15, row=(lane>>4)*4+reg.
// Fallback: R3's proven monolithic kernel if ws too small.

using f32x4  = __attribute__((ext_vector_type(4))) float;
using f32x2  = __attribute__((ext_vector_type(2))) float;
using bf16x8 = __attribute__((ext_vector_type(8))) __bf16;
using bf16x4 = __attribute__((ext_vector_type(4))) __bf16;

struct BfPair { __bf16 hi, lo; };
__device__ inline BfPair split_bf16(float x) {
    BfPair p;
    p.hi = (__bf16)x;
    p.lo = (__bf16)(x - (float)p.hi);
    return p;
}

// ---------------- LDS shapes ------------------------------------------------
struct RoutSM {
    float spart[16][1024];  // 64 KB: per-wave partial s
    float u_s[1024];        //  4 KB: y staged for the dots
    float b_s[64], d_s[64], red_s[16], scale_s;
};
struct QSmem {
    __bf16 a_hi[64 * 64];
    __bf16 a_lo[64 * 64];
    __bf16 b_hi[64 * 64];
    __bf16 b_lo[64 * 64];
};

// ---------------- routing body (R12-exact, 186us-proven) --------------------
// Block = capsule c, 16 waves. Wave w owns enc rows w*4..w*4+3; lane holds
// 16 floats/row. MODE 0: d uniform. MODE 1: b = scale*(E.y). MODE 2: +=.
template <int MODE>
__device__ __forceinline__ void routing_body(
    int c, const float* __restrict__ enc, const float* __restrict__ y0,
    const float* __restrict__ y1, float* __restrict__ bglob,
    __bf16* __restrict__ s_hi, __bf16* __restrict__ s_lo, RoutSM* sm)
{
    const int t = threadIdx.x, lane = t & 63, w = t >> 6;   // 16 waves
    const float* E = enc + (size_t)c * 65536;

    // small prologue loads first so their waitcnt doesn't drain er loads
    float yv = 0.f, sv = 0.f;
    if (MODE > 0) {
        const size_t o = (size_t)c * 1024 + t;
        yv = y0[o] + y1[o];                       // y = Q s (full K)
        sv = (float)s_hi[o] + (float)s_lo[o];     // s as the gemm saw it
    }

    f32x4 er[4][4];                     // enc tile
    #pragma unroll
    for (int r = 0; r < 4; ++r) {
        const float* ek = E + (size_t)(w * 4 + r) * 1024 + lane * 8;
        er[r][0] = *(const f32x4*)(ek);
        er[r][1] = *(const f32x4*)(ek + 4);
        er[r][2] = *(const f32x4*)(ek + 512);
        er[r][3] = *(const f32x4*)(ek + 516);
    }

    if (MODE > 0) {
        sm->u_s[t] = yv;
        float p = yv * sv;                        // norm = s^T Q s = |W s|^2
        #pragma unroll
        for (int off = 32; off; off >>= 1) p += __shfl_xor(p, off, 64);
        if (lane == 0) sm->red_s[w] = p;
        __syncthreads();
        if (t == 0) {
            float n = 0.f;
            #pragma unroll
            for (int i = 0; i < 16; ++i) n += sm->red_s[i];
            sm->scale_s = n / ((1.f + n) * sqrtf(n) + 1e-30f);
        }
        __syncthreads();
        const float scale = sm->scale_s;
        f32x4 uf[4];
        uf[0] = *(const f32x4*)&sm->u_s[lane * 8];
        uf[1] = *(const f32x4*)&sm->u_s[lane * 8 + 4];
        uf[2] = *(const f32x4*)&sm->u_s[512 + lane * 8];
        uf[3] = *(const f32x4*)&sm->u_s[512 + lane * 8 + 4];
        #pragma unroll
        for (int r = 0; r < 4; ++r) {
            float sum = 0.f;
            #pragma unroll
            for (int q = 0; q < 4; ++q)
                #pragma unroll
                for (int j = 0; j < 4; ++j)
                    sum += er[r][q][j] * uf[q][j];
            #pragma unroll
            for (int off = 32; off; off >>= 1) sum += __shfl_xor(sum, off, 64);
            if (lane == 0) {
                const int k = w * 4 + r;
                const float bv =
                    (MODE == 2 ? bglob[c * 64 + k] : 0.f) + scale * sum;
                bglob[c * 64 + k] = bv;     // persist for next iteration
                sm->b_s[k] = bv;
            }
        }
    }
    __syncthreads();

    if (MODE == 0) {
        if (t < 64) sm->d_s[t] = 1.f / 64.f;
    } else if (t < 64) {
        float bv = sm->b_s[t], m = bv;
        #pragma unroll
        for (int off = 32; off; off >>= 1) m = fmaxf(m, __shfl_xor(m, off, 64));
        const float e = expf(bv - m);
        float smm = e;
        #pragma unroll
        for (int off = 32; off; off >>= 1) smm += __shfl_xor(smm, off, 64);
        sm->d_s[t] = e / smm;
    }
    __syncthreads();

    // per-wave partial s from registers (4 rows each)
    #pragma unroll
    for (int q = 0; q < 4; ++q) {
        f32x4 p = {};
        #pragma unroll
        for (int r = 0; r < 4; ++r) {
            const float dk = sm->d_s[w * 4 + r];
            #pragma unroll
            for (int j = 0; j < 4; ++j) p[j] += dk * er[r][q][j];
        }
        const int h = (q >> 1) * 512 + lane * 8 + (q & 1) * 4;
        *(f32x4*)&sm->spart[w][h] = p;
    }
    __syncthreads();

    // cross-wave reduce: 1 h-element per thread; emit split-bf16 s
    {
        float a = 0.f;
        #pragma unroll
        for (int wv = 0; wv < 16; ++wv) a += sm->spart[wv][t];
        const BfPair p = split_bf16(a);
        s_hi[(size_t)c * 1024 + t] = p.hi;
        s_lo[(size_t)c * 1024 + t] = p.lo;
    }
}

// ---------------- Q tile from W: 16 waves, transpose-staged -----------------
// Tile (ti,tj), ti<=tj (triangular, mirror-written). Staging: thread t,
// half = t>>9 (0:A from W cols ti*64.., 1:B from W cols tj*64..),
// m=(t&511)>>3, k8=(t&7)*8. Per K-step: 8 coalesced 4B loads
// W[k0+k8+j][col0+m] (lanes m consecutive -> 256B transactions, L2-
// resident), split_bf16, pack, ONE swizzled bf16x8 LDS write. MFMA body
// identical to the R13/R17/R18-verified gemm64_16w.
__device__ __forceinline__ int swz128(int row, int colbyte) {
    return row * 128 + (colbyte ^ ((row & 7) << 4));
}

__device__ __forceinline__ void q_from_w_body(
    const float* __restrict__ W, __bf16* __restrict__ Qh,
    __bf16* __restrict__ Ql, int qb, QSmem* sm)
{
    // triangular index: tile (ti,tj) with ti <= tj, qb = T(tj) + ti
    int tj = (int)((sqrtf(8.f * (float)qb + 1.f) - 1.f) * 0.5f);
    while ((tj + 1) * (tj + 2) / 2 <= qb) ++tj;
    while (tj * (tj + 1) / 2 > qb) --tj;
    const int ti = qb - tj * (tj + 1) / 2;

    const int t = threadIdx.x, lane = t & 63, w = t >> 6;
    const int wr = w >> 2, wc = w & 3;          // 4x4 wave grid
    const int half = t >> 9;                    // 0: stage A, 1: stage B
    const int m    = (t & 511) >> 3;            // bf16 row 0..63
    const int k8   = (t & 7) * 8;               // k element offset
    const int scb  = (t & 7) * 16;              // col byte
    const int col0 = (half ? tj : ti) * 64;
    char* const p_hi = (char*)(half ? sm->b_hi : sm->a_hi) + swz128(m, scb);
    char* const p_lo = (char*)(half ? sm->b_lo : sm->a_lo) + swz128(m, scb);

    f32x4 acc = {};
    for (int k0 = 0; k0 < 1024; k0 += 64) {
        __syncthreads();                        // prev LDS use done
        bf16x8 hv, lv;
        #pragma unroll
        for (int j = 0; j < 8; ++j) {
            const float v = W[(size_t)(k0 + k8 + j) * 1024 + col0 + m];
            const BfPair p = split_bf16(v);
            hv[j] = p.hi;
            lv[j] = p.lo;
        }
        *(bf16x8*)p_hi = hv;
        *(bf16x8*)p_lo = lv;
        __syncthreads();
        #pragma unroll
        for (int kk = 0; kk < 2; ++kk) {
            const int cb = kk * 64 + (lane >> 4) * 16;
            const int mm = wr * 16 + (lane & 15);
            const int nn = wc * 16 + (lane & 15);
            const bf16x8 ah = *(const bf16x8*)((char*)sm->a_hi + swz128(mm, cb));
            const bf16x8 al = *(const bf16x8*)((char*)sm->a_lo + swz128(mm, cb));
            const bf16x8 bh = *(const bf16x8*)((char*)sm->b_hi + swz128(nn, cb));
            const bf16x8 bl = *(const bf16x8*)((char*)sm->b_lo + swz128(nn, cb));
            acc = __builtin_amdgcn_mfma_f32_16x16x32_bf16(ah, bh, acc, 0, 0, 0);
            acc = __builtin_amdgcn_mfma_f32_16x16x32_bf16(ah, bl, acc, 0, 0, 0);
            acc = __builtin_amdgcn_mfma_f32_16x16x32_bf16(al, bh, acc, 0, 0, 0);
        }
    }
    const int rr = (lane >> 4) * 4, colb = lane & 15;
    bf16x4 hv, lv;
    #pragma unroll
    for (int r = 0; r < 4; ++r) {
        const BfPair p = split_bf16(acc[r]);
        const size_t idx = (size_t)(ti * 64 + wr * 16 + rr + r) * 1024 +
                           tj * 64 + wc * 16 + colb;
        Qh[idx] = p.hi;
        Ql[idx] = p.lo;
        hv[r] = p.hi;
        lv[r] = p.lo;
    }
    if (ti != tj) {     // Q symmetric: packed 8B store into the transpose
        const size_t midx = (size_t)(tj * 64 + wc * 16 + colb) * 1024 +
                            ti * 64 + wr * 16 + rr;
        *(bf16x4*)(Qh + midx) = hv;
        *(bf16x4*)(Ql + midx) = lv;
    }
}

// Dispatch A (WITH_EXTRA=1): [0,256) routing0, [256,392) Q tiles,
// [392,424) convWb. All pure input readers -> zero sync.
// C/E (WITH_EXTRA=0): 256 routing blocks only.
template <int MODE, int WITH_EXTRA>
__global__ __launch_bounds__(1024, 4) void routing_kernel(
    const float* __restrict__ enc, const float* __restrict__ y0,
    const float* __restrict__ y1, float* __restrict__ bglob,
    __bf16* __restrict__ s_hi, __bf16* __restrict__ s_lo,
    const float* __restrict__ W, __bf16* __restrict__ Q_hi,
    __bf16* __restrict__ Q_lo, __bf16* __restrict__ Wb_hi,
    __bf16* __restrict__ Wb_lo)
{
    __shared__ union {
        RoutSM r;
        QSmem q;
    } sm;

    const int b = blockIdx.x;
    if (WITH_EXTRA && b >= 256) {
        if (b < 392) {                  // Q = W^T W, triangular tile
            q_from_w_body(W, Q_hi, Q_lo, b - 256, &sm.q);
        } else {                        // W -> split-bf16 Wb (coalesced)
            const int bb = b - 392, t = threadIdx.x;
            #pragma unroll
            for (int q = 0; q < 8; ++q) {
                const size_t idx =
                    (size_t)bb * 32768 + (size_t)q * 4096 + t * 4;
                const f32x4 v = *(const f32x4*)(W + idx);
                bf16x4 hv, lv;
                #pragma unroll
                for (int j = 0; j < 4; ++j) {
                    const BfPair p = split_bf16(v[j]);
                    hv[j] = p.hi;
                    lv[j] = p.lo;
                }
                *(bf16x4*)(Wb_hi + idx) = hv;
                *(bf16x4*)(Wb_lo + idx) = lv;
            }
        }
        return;
    }
    routing_body<MODE>(b, enc, y0, y1, bglob, s_hi, s_lo, &sm.r);
}

// ---- tiled split-bf16 NT GEMM, split-K x2 (R12/R16-verified) --------------
// 128 blocks: kh=bx&1, task=bx>>1 -> mt (4 x 64 rows), nt (16 x 64 cols).
// 256 thr = 4 waves (2x2 of 32x32). BK=64 LDS staging, swizzled.
__global__ __launch_bounds__(256) void gemm_nt_kernel(
    const __bf16* __restrict__ Ah, const __bf16* __restrict__ Al,
    const __bf16* __restrict__ Bh, const __bf16* __restrict__ Bl,
    float* __restrict__ C0, float* __restrict__ C1)
{
    __shared__ QSmem sm;
    const int kh   = blockIdx.x & 1;
    const int task = blockIdx.x >> 1;
    const int mt   = task >> 4;                 // 0..3   (64-row panel)
    const int nt   = task & 15;                 // 0..15  (64-col panel)
    const int t = threadIdx.x;
    const int lane = t & 63, w = t >> 6;        // 4 waves
    const int wr = w >> 1, wc = w & 1;          // wave's 32x32 sub-tile
    const int sr  = t >> 2;                     // row 0..63
    const int scb = (t & 3) * 16;               // col byte {0,16,32,48}
    const size_t ga = (size_t)(mt * 64 + sr) * 1024 + kh * 512 + scb / 2;
    const size_t gb = (size_t)(nt * 64 + sr) * 1024 + kh * 512 + scb / 2;

    f32x4 acc[2][2] = {};
    for (int k0 = 0; k0 < 512; k0 += 64) {
        if (k0) __syncthreads();                // prev step's reads done
        #pragma unroll
        for (int h = 0; h < 2; ++h) {
            const int cb = scb + h * 64;        // covers full 128-B row
            const size_t gao = ga + h * 32 + k0;
            const size_t gbo = gb + h * 32 + k0;
            *(bf16x8*)((char*)sm.a_hi + swz128(sr, cb)) = *(const bf16x8*)(Ah + gao);
            *(bf16x8*)((char*)sm.a_lo + swz128(sr, cb)) = *(const bf16x8*)(Al + gao);
            *(bf16x8*)((char*)sm.b_hi + swz128(sr, cb)) = *(const bf16x8*)(Bh + gbo);
            *(bf16x8*)((char*)sm.b_lo + swz128(sr, cb)) = *(const bf16x8*)(Bl + gbo);
        }
        __syncthreads();
        #pragma unroll
        for (int kk = 0; kk < 2; ++kk) {
            const int cb = kk * 64 + (lane >> 4) * 16;  // col byte of frag
            bf16x8 ah[2], al[2], bh[2], bl[2];
            #pragma unroll
            for (int mi = 0; mi < 2; ++mi) {
                const int m = wr * 32 + mi * 16 + (lane & 15);
                ah[mi] = *(const bf16x8*)((char*)sm.a_hi + swz128(m, cb));
                al[mi] = *(const bf16x8*)((char*)sm.a_lo + swz128(m, cb));
            }
            #pragma unroll
            for (int ni = 0; ni < 2; ++ni) {
                const int n = wc * 32 + ni * 16 + (lane & 15);
                bh[ni] = *(const bf16x8*)((char*)sm.b_hi + swz128(n, cb));
                bl[ni] = *(const bf16x8*)((char*)sm.b_lo + swz128(n, cb));
            }
            #pragma unroll
            for (int mi = 0; mi < 2; ++mi)
                #pragma unroll
                for (int ni = 0; ni < 2; ++ni) {
                    f32x4 a = acc[mi][ni];
                    a = __builtin_amdgcn_mfma_f32_16x16x32_bf16(ah[mi], bh[ni], a, 0, 0, 0);
                    a = __builtin_amdgcn_mfma_f32_16x16x32_bf16(ah[mi], bl[ni], a, 0, 0, 0);
                    a = __builtin_amdgcn_mfma_f32_16x16x32_bf16(al[mi], bh[ni], a, 0, 0, 0);
                    acc[mi][ni] = a;
                }
        }
    }
    float* Cc = kh ? C1 : C0;
    const int rr = (lane >> 4) * 4, colb = lane & 15;
    #pragma unroll
    for (int mi = 0; mi < 2; ++mi)
        #pragma unroll
        for (int ni = 0; ni < 2; ++ni)
            #pragma unroll
            for (int r = 0; r < 4; ++r)
                Cc[(size_t)(mt * 64 + wr * 32 + mi * 16 + rr + r) * 1024 +
                   nt * 64 + wc * 32 + ni * 16 + colb] = acc[mi][ni][r];
}

// ---------------- final squash: sums split-K chat, emits out ---------------
__global__ __launch_bounds__(256) void squash_out_kernel(
    const float* __restrict__ chat0, const float* __restrict__ chat1,
    float* __restrict__ outp)
{
    __shared__ float wsum[4];
    const int c = blockIdx.x, t = threadIdx.x;
    const int lane = t & 63, w = t >> 6;
    const size_t o = (size_t)c * 1024 + t * 4;
    f32x4 v = *(const f32x4*)(chat0 + o) + *(const f32x4*)(chat1 + o);
    float ss = v[0]*v[0] + v[1]*v[1] + v[2]*v[2] + v[3]*v[3];
    #pragma unroll
    for (int off = 32; off; off >>= 1) ss += __shfl_xor(ss, off, 64);
    if (lane == 0) wsum[w] = ss;
    __syncthreads();
    const float norm = wsum[0] + wsum[1] + wsum[2] + wsum[3];
    const float scale = norm / ((1.f + norm) * sqrtf(norm) + 1e-30f);
    *(f32x4*)(outp + o) = v * scale;
}

// ---------------- fallback: R3's proven monolithic fp32 kernel --------------
__global__ __launch_bounds__(512) void fallback_kernel(
    const float* __restrict__ enc, const float* __restrict__ W,
    float* __restrict__ outp)
{
    __shared__ float u_s[1024], s_s[1024], c_s[1024], chat_s[1024];
    __shared__ float b_s[64], d_s[64], red_s[8];
    const int t = threadIdx.x, lane = t & 63, w = t >> 6;
    const float* erow = enc + (size_t)blockIdx.x * 65536;

    if (t < 64) b_s[t] = 0.f;
    __syncthreads();

    for (int it = 0; it < 3; ++it) {
        if (it > 0) {
            f32x4 uf[4];
            #pragma unroll
            for (int q = 0; q < 2; ++q) {
                uf[2*q]   = *(const f32x4*)&u_s[q*512 + lane*8];
                uf[2*q+1] = *(const f32x4*)&u_s[q*512 + lane*8 + 4];
            }
            for (int r = 0; r < 8; ++r) {
                const int k = w * 8 + r;
                const float* ek = erow + (size_t)k * 1024;
                float sum = 0.f;
                #pragma unroll
                for (int q = 0; q < 2; ++q) {
                    f32x4 e0 = *(const f32x4*)(ek + q*512 + lane*8);
                    f32x4 e1 = *(const f32x4*)(ek + q*512 + lane*8 + 4);
                    #pragma unroll
                    for (int j = 0; j < 4; ++j) {
                        sum += e0[j] * uf[2*q][j];
                        sum += e1[j] * uf[2*q+1][j];
                    }
                }
                #pragma unroll
                for (int off = 32; off; off >>= 1) sum += __shfl_xor(sum, off, 64);
                if (lane == 0) b_s[k] += sum;
            }
            __syncthreads();
        }
        if (t < 64) {
            float bv = b_s[t], m = bv;
            #pragma unroll
            for (int off = 32; off; off >>= 1) m = fmaxf(m, __shfl_xor(m, off, 64));
            float e = expf(bv - m), sm = e;
            #pragma unroll
            for (int off = 32; off; off >>= 1) sm += __shfl_xor(sm, off, 64);
            d_s[t] = e / sm;
        }
        __syncthreads();
        {
            const int h0 = t * 2;
            float a0 = 0.f, a1 = 0.f;
            for (int k = 0; k < 64; ++k) {
                f32x2 ev = *(const f32x2*)(erow + (size_t)k * 1024 + h0);
                a0 += d_s[k] * ev[0]; a1 += d_s[k] * ev[1];
            }
            s_s[h0] = a0; s_s[h0+1] = a1;
        }
        __syncthreads();
        {
            f32x4 sf[4];
            #pragma unroll
            for (int q = 0; q < 2; ++q) {
                sf[2*q]   = *(const f32x4*)&s_s[q*512 + lane*8];
                sf[2*q+1] = *(const f32x4*)&s_s[q*512 + lane*8 + 4];
            }
            for (int r = 0; r < 128; ++r) {
                const int d = w * 128 + r;
                const float* wr = W + (size_t)d * 1024;
                float sum = 0.f;
                #pragma unroll
                for (int q = 0; q < 2; ++q) {
                    f32x4 w0 = *(const f32x4*)(wr + q*512 + lane*8);
                    f32x4 w1 = *(const f32x4*)(wr + q*512 + lane*8 + 4);
                    #pragma unroll
                    for (int j = 0; j < 4; ++j) {
                        sum += w0[j] * sf[2*q][j];
                        sum += w1[j] * sf[2*q+1][j];
                    }
                }
                #pragma unroll
                for (int off = 32; off; off >>= 1) sum += __shfl_xor(sum, off, 64);
                if (lane == 0) chat_s[d] = sum;
            }
        }
        __syncthreads();
        {
            const int h0 = t * 2;
            float v0 = chat_s[h0], v1 = chat_s[h0+1];
            float ss = v0*v0 + v1*v1;
            #pragma unroll
            for (int off = 32; off; off >>= 1) ss += __shfl_xor(ss, off, 64);
            if (lane == 0) red_s[w] = ss;
            __syncthreads();
            float norm = 0.f;
            #pragma unroll
            for (int i = 0; i < 8; ++i) norm += red_s[i];
            const float scale = norm / ((1.f + norm) * sqrtf(norm) + 1e-30f);
            c_s[h0] = v0 * scale; c_s[h0+1] = v1 * scale;
        }
        __syncthreads();
        if (it < 2) {
            const int h0 = t * 2;
            float uu0 = 0.f, uu1 = 0.f;
            for (int d = 0; d < 1024; ++d) {
                f32x2 wv = *(const f32x2*)(W + (size_t)d * 1024 + h0);
                uu0 += c_s[d] * wv[0]; uu1 += c_s[d] * wv[1];
            }
            u_s[h0] = uu0; u_s[h0+1] = uu1;
        } else {
            const int h0 = t * 2;
            f32x2 ov; ov[0] = c_s[h0]; ov[1] = c_s[h0+1];
            *(f32x2*)(outp + (size_t)blockIdx.x * 1024 + h0) = ov;
        }
        __syncthreads();
    }
}

extern "C" void kernel_launch(void* const* d_in, const int* in_sizes, int n_in,
                              void* d_out, int out_size, void* d_ws, size_t ws_size,
                              hipStream_t stream)
{
    const float* enc = (const float*)d_in[0];   // [256,64,1024] fp32
    const float* W   = (const float*)d_in[1];   // [1024,1024]   fp32
    float* outp = (float*)d_out;                // [256,1024]    fp32
    (void)in_sizes; (void)n_in; (void)out_size;

    // ws layout (11.5 MB)
    char* ws = (char*)d_ws;
    float*  b     = (float*) (ws + 0x000000);  //  64 KB [256,64]
    __bf16* s_hi  = (__bf16*)(ws + 0x080000);  // 512 KB [256,1024]
    __bf16* s_lo  = (__bf16*)(ws + 0x100000);  // 512 KB
    float*  y0    = (float*) (ws + 0x180000);  //   1 MB (y / chat, split-K lo)
    float*  y1    = (float*) (ws + 0x280000);  //   1 MB (y / chat, split-K hi)
    __bf16* Wb_hi = (__bf16*)(ws + 0x380000);  //   2 MB [d,h] split
    __bf16* Wb_lo = (__bf16*)(ws + 0x580000);  //   2 MB
    __bf16* Q_hi  = (__bf16*)(ws + 0x780000);  //   2 MB [1024,1024]
    __bf16* Q_lo  = (__bf16*)(ws + 0x980000);  //   2 MB

    if (ws_size < 0xB80000) {
        fallback_kernel<<<256, 512, 0, stream>>>(enc, W, outp);
        return;
    }

    // A: routing0 | Q = W^T W (from W, triangular+mirror) | convWb
    routing_kernel<0, 1><<<424, 1024, 0, stream>>>(
        enc, y0, y1, b, s_hi, s_lo, W, Q_hi, Q_lo, Wb_hi, Wb_lo);

    // B: y = Q s (tiled, split-K x2)
    gemm_nt_kernel<<<128, 256, 0, stream>>>(
        s_hi, s_lo, Q_hi, Q_lo, y0, y1);

    // C: routing iter1 (norm = s.y -> scale; b = scale*(E.y); new s)
    routing_kernel<1, 0><<<256, 1024, 0, stream>>>(
        enc, y0, y1, b, s_hi, s_lo, nullptr, nullptr, nullptr,
        nullptr, nullptr);

    // D: y = Q s
    gemm_nt_kernel<<<128, 256, 0, stream>>>(
        s_hi, s_lo, Q_hi, Q_lo, y0, y1);

    // E: routing iter2 (b += scale*(E.y); final s)
    routing_kernel<2, 0><<<256, 1024, 0, stream>>>(
        enc, y0, y1, b, s_hi, s_lo, nullptr, nullptr, nullptr,
        nullptr, nullptr);

    // F: chat = W s (tiled, B = Wb)
    gemm_nt_kernel<<<128, 256, 0, stream>>>(
        s_hi, s_lo, Wb_hi, Wb_lo, y0, y1);

    // G: out = squash(chat)
    squash_out_kernel<<<256, 256, 0, stream>>>(y0, y1, outp);
}

// Round 13
// 218.965 us; speedup vs baseline: 3.8161x; 1.0060x over previous
//
#include <hip/hip_runtime.h>

// InductionNetwork capsule routing, C=256, K=64, H=1024, 3 iterations.
// R20: R16's proven 8-dispatch pipeline (186-188us) + STREAMING routing.
// R19 diagnosis: routing ran at ~700 GB/s because register-based
// streaming is bytes-in-flight starved (8 waves/EU target -> <=64 VGPR
// -> ~1KB/SIMD outstanding -> ~2-3 TB/s cap). Escape: global_load_lds
// puts 1KB/wave in flight PER INSTRUCTION with zero VGPR cost. Routing
// now streams enc in 8-row (32KB) chunks, double-buffered in LDS, with
// the m201-proven counted-vmcnt + raw s_barrier + sched_barrier pattern
// (prefetch never drained). MODE>0: pass1 dots -> softmax -> pass2
// weighted sum (pass2 L3-warm). MODE0: single pass. Column-parallel
// dots (lane owns col t, x y[t], wave-reduce) also kill the old spart
// 16-way bank conflicts. All sync is intra-block -> no hang risk.
// Dispatches (8, R16-exact):
//   A convwt||routing0   W -> Wt split-bf16 ; s = mean_k enc
//   B gemm_Q             Q = Wt Wt^T (136 triangular tiles + mirrors)
//   C gemm_y0||convWb    y = Q s (tiled) ; W -> Wb into Wx (Wt dead)
//   D routing1           norm=s.y -> scale; b = scale*(E.y); s
//   E gemm_y1            y = Q s (tiled)
//   F routing2           b += scale*(E.y); s
//   G gemm_chat          chat = W s (tiled, B = Wb)
//   H squash_out         out = squash(chat)
// Split-bf16 operands (verified R6-R19, absmax 4.88e-4):
//   D = Ah.Bh + Ah.Bl + Al.Bh with hi=bf16(x), lo=bf16(x-hi).
// Fallback: R3's proven monolithic kernel if ws too small.

using f32x4  = __attribute__((ext_vector_type(4))) float;
using f32x2  = __attribute__((ext_vector_type(2))) float;
using bf16x8 = __attribute__((ext_vector_type(8))) __bf16;
using bf16x4 = __attribute__((ext_vector_type(4))) __bf16;

struct BfPair { __bf16 hi, lo; };
__device__ inline BfPair split_bf16(float x) {
    BfPair p;
    p.hi = (__bf16)x;
    p.lo = (__bf16)(x - (float)p.hi);
    return p;
}

// ---------------- LDS shapes ------------------------------------------------
struct RoutSM {
    float chunk[2][8][1024];    // 64 KB: double-buffered enc chunks
    float bpart[16][64];        //  4 KB: per-wave row-dot partials
    float bold[64];             // prior b (MODE2) or 0
    float d_s[64], red_s[16], scale_s;
};
struct QSmem {
    __bf16 a_hi[64 * 64];
    __bf16 a_lo[64 * 64];
    __bf16 b_hi[64 * 64];
    __bf16 b_lo[64 * 64];
};

// ---------------- async global->LDS staging ---------------------------------
// Chunk ck = enc rows [ck*8, ck*8+8) of this capsule = 32 KB. Two 16B
// issues per thread: bytes [t*16] and [16384 + t*16]. LDS dest is
// wave-uniform base + lane*16 (HW rule); mapping is exactly linear.
typedef const __attribute__((address_space(1))) unsigned int* GASP;
typedef __attribute__((address_space(3))) unsigned int* LASP;

__device__ __forceinline__ void stage_chunk(
    const float* __restrict__ E, float* __restrict__ chunkbase,
    int t, int w, int ck, int cb)
{
    const float* s1 = E + (size_t)ck * 8192 + (size_t)t * 4;
    float* d1 = chunkbase + cb * 8192 + w * 256;
    __builtin_amdgcn_global_load_lds((GASP)s1, (LASP)d1, 16, 0, 0);
    __builtin_amdgcn_global_load_lds((GASP)(s1 + 4096), (LASP)(d1 + 4096),
                                     16, 0, 0);
}

// counted-vmcnt chunk-ready barrier (prefetch of next chunk stays in
// flight across the barrier -- T3/T4 pattern, m201-proven)
#define CHUNK_READY(ck)                                                  \
    do {                                                                 \
        if ((ck) < 7) asm volatile("s_waitcnt vmcnt(2)" ::: "memory");   \
        else          asm volatile("s_waitcnt vmcnt(0)" ::: "memory");   \
        __builtin_amdgcn_sched_barrier(0);                               \
        __builtin_amdgcn_s_barrier();                                    \
        __builtin_amdgcn_sched_barrier(0);                               \
    } while (0)

#define CHUNK_FREE()                                                     \
    do {                                                                 \
        asm volatile("s_waitcnt lgkmcnt(0)" ::: "memory");               \
        __builtin_amdgcn_sched_barrier(0);                               \
        __builtin_amdgcn_s_barrier();                                    \
        __builtin_amdgcn_sched_barrier(0);                               \
    } while (0)

// ---------------- streaming routing body ------------------------------------
// Block = capsule c, 16 waves. Lane owns column t = w*64+lane.
// MODE 0: s = mean_k enc (single pass). MODE 1: b = scale*(E.y), s.
// MODE 2: b += scale*(E.y), s.
template <int MODE>
__device__ __forceinline__ void routing_body(
    int c, const float* __restrict__ enc, const float* __restrict__ y0,
    const float* __restrict__ y1, float* __restrict__ bglob,
    __bf16* __restrict__ s_hi, __bf16* __restrict__ s_lo, RoutSM* sm)
{
    const int t = threadIdx.x, lane = t & 63, w = t >> 6;   // 16 waves
    const float* E = enc + (size_t)c * 65536;
    float* const cbase = &sm->chunk[0][0][0];

    // prologue: y value for this column; norm = s.y -> scale; old b
    float yv = 0.f;
    if (MODE > 0) {
        const size_t o = (size_t)c * 1024 + t;
        yv = y0[o] + y1[o];                       // y = Q s (full K)
        const float sv = (float)s_hi[o] + (float)s_lo[o];
        float p = yv * sv;                        // norm = s^T Q s = |W s|^2
        #pragma unroll
        for (int off = 32; off; off >>= 1) p += __shfl_xor(p, off, 64);
        if (lane == 0) sm->red_s[w] = p;
        if (t < 64) sm->bold[t] = (MODE == 2) ? bglob[c * 64 + t] : 0.f;
        __syncthreads();                          // prologue loads drained
        if (t == 0) {
            float n = 0.f;
            #pragma unroll
            for (int i = 0; i < 16; ++i) n += sm->red_s[i];
            sm->scale_s = n / ((1.f + n) * sqrtf(n) + 1e-30f);
        }
    }

    stage_chunk(E, cbase, t, w, 0, 0);
    stage_chunk(E, cbase, t, w, 1, 1);

    if (MODE > 0) {
        // ---- pass 1: dots b_k = sum_h enc[k][h]*y[h] ----
        #pragma unroll
        for (int ck = 0; ck < 8; ++ck) {
            CHUNK_READY(ck);
            const int cb = ck & 1;
            #pragma unroll
            for (int r = 0; r < 8; ++r) {
                float p = sm->chunk[cb][r][t] * yv;
                #pragma unroll
                for (int off = 32; off; off >>= 1)
                    p += __shfl_xor(p, off, 64);
                if (lane == 0) sm->bpart[w][ck * 8 + r] = p;
            }
            CHUNK_FREE();
            if (ck < 6) stage_chunk(E, cbase, t, w, ck + 2, cb);
        }
        // ---- combine + softmax (wave 0 exactly) ----
        if (t < 64) {
            float sum = 0.f;
            #pragma unroll
            for (int wv = 0; wv < 16; ++wv) sum += sm->bpart[wv][t];
            const float bv = sm->bold[t] + sm->scale_s * sum;
            bglob[c * 64 + t] = bv;               // persist for next iter
            float m = bv;
            #pragma unroll
            for (int off = 32; off; off >>= 1)
                m = fmaxf(m, __shfl_xor(m, off, 64));
            const float e = expf(bv - m);
            float smm = e;
            #pragma unroll
            for (int off = 32; off; off >>= 1)
                smm += __shfl_xor(smm, off, 64);
            sm->d_s[t] = e / smm;
        }
        // re-issue for pass 2 (buffers free after last CHUNK_FREE);
        // softmax latency hides the HBM/L3 roundtrip
        stage_chunk(E, cbase, t, w, 0, 0);
        stage_chunk(E, cbase, t, w, 1, 1);
        asm volatile("s_waitcnt lgkmcnt(0)" ::: "memory");
        __builtin_amdgcn_sched_barrier(0);
        __builtin_amdgcn_s_barrier();             // d_s visible
        __builtin_amdgcn_sched_barrier(0);
    }

    // ---- pass 2: s[t] = sum_k d_k * enc[k][t]  (L3-warm for MODE>0) ----
    float acc = 0.f;
    #pragma unroll
    for (int ck = 0; ck < 8; ++ck) {
        CHUNK_READY(ck);
        const int cb = ck & 1;
        #pragma unroll
        for (int r = 0; r < 8; ++r) {
            const float dk = (MODE == 0) ? 0.015625f : sm->d_s[ck * 8 + r];
            acc += dk * sm->chunk[cb][r][t];
        }
        CHUNK_FREE();
        if (ck < 6) stage_chunk(E, cbase, t, w, ck + 2, cb);
    }

    const BfPair p = split_bf16(acc);
    s_hi[(size_t)c * 1024 + t] = p.hi;
    s_lo[(size_t)c * 1024 + t] = p.lo;
}

// Routing dispatch. WITH_CONV: blocks [0,256) do W -> Wt split-bf16
// (transposed, 64x64 LDS tiles); routing capsules are blocks [256,512).
template <int MODE, int WITH_CONV>
__global__ __launch_bounds__(1024) void routing_kernel(
    const float* __restrict__ enc, const float* __restrict__ y0,
    const float* __restrict__ y1, float* __restrict__ bglob,
    __bf16* __restrict__ s_hi, __bf16* __restrict__ s_lo,
    const float* __restrict__ W, __bf16* __restrict__ Wt_hi,
    __bf16* __restrict__ Wt_lo)
{
    __shared__ union {
        RoutSM r;
        float tile[64][65];     // 16.6 KB: conv transpose staging
    } sm;

    int c = blockIdx.x;
    if (WITH_CONV) {
        if (blockIdx.x < 256) {
            const int by = blockIdx.x >> 4, bx = blockIdx.x & 15;
            const int tx = threadIdx.x & 63, ty = threadIdx.x >> 6;
            for (int i = ty; i < 64; i += 16)
                sm.tile[i][tx] = W[(size_t)(by * 64 + i) * 1024 + bx * 64 + tx];
            __syncthreads();
            for (int i = ty; i < 64; i += 16) {
                const size_t idx = (size_t)(bx * 64 + i) * 1024 + by * 64 + tx;
                const BfPair p = split_bf16(sm.tile[tx][i]);
                Wt_hi[idx] = p.hi;
                Wt_lo[idx] = p.lo;
            }
            return;
        }
        c = blockIdx.x - 256;
    }
    routing_body<MODE>(c, enc, y0, y1, bglob, s_hi, s_lo, &sm.r);
}

// ---------------- LDS-tiled GEMM machinery (R16-exact) ----------------------
__device__ __forceinline__ int swz128(int row, int colbyte) {
    // 128-byte rows; XOR bits 4-6 of the byte offset with row&7
    return row * 128 + (colbyte ^ ((row & 7) << 4));
}

// ---- Q = Wt Wt^T (= W^T W): SYMMETRIC -> 136 upper-triangle tiles
// (ti <= tj), mirror-write off-diagonal tiles. 256 threads = 4 waves in a
// 2x2 grid, each wave a 32x32 sub-tile (2x2 16x16 frags), BK=64 LDS
// staging, XOR-swizzled rows. Writes split-bf16 Q. (verified R16)
__global__ __launch_bounds__(256) void gemm_q_kernel(
    const __bf16* __restrict__ Wt_hi, const __bf16* __restrict__ Wt_lo,
    __bf16* __restrict__ Q_hi, __bf16* __restrict__ Q_lo)
{
    __shared__ QSmem sm;
    const int b = blockIdx.x;
    int tj = (int)((sqrtf(8.f * (float)b + 1.f) - 1.f) * 0.5f);
    while ((tj + 1) * (tj + 2) / 2 <= b) ++tj;
    while (tj * (tj + 1) / 2 > b) --tj;
    const int ti = b - tj * (tj + 1) / 2;

    const int t = threadIdx.x;
    const int lane = t & 63, w = t >> 6;        // 4 waves
    const int wr = w >> 1, wc = w & 1;          // wave's 32x32 sub-tile
    const int sr  = t >> 2;                     // row 0..63
    const int scb = (t & 3) * 16;               // col byte {0,16,32,48}
    const size_t ga = (size_t)(ti * 64 + sr) * 1024 + scb / 2;
    const size_t gb = (size_t)(tj * 64 + sr) * 1024 + scb / 2;

    f32x4 acc[2][2] = {};
    for (int k0 = 0; k0 < 1024; k0 += 64) {
        if (k0) __syncthreads();                // prev step's reads done
        #pragma unroll
        for (int h = 0; h < 2; ++h) {
            const int cb = scb + h * 64;        // covers full 128-B row
            const size_t gao = ga + h * 32 + k0;
            const size_t gbo = gb + h * 32 + k0;
            *(bf16x8*)((char*)sm.a_hi + swz128(sr, cb)) = *(const bf16x8*)(Wt_hi + gao);
            *(bf16x8*)((char*)sm.a_lo + swz128(sr, cb)) = *(const bf16x8*)(Wt_lo + gao);
            *(bf16x8*)((char*)sm.b_hi + swz128(sr, cb)) = *(const bf16x8*)(Wt_hi + gbo);
            *(bf16x8*)((char*)sm.b_lo + swz128(sr, cb)) = *(const bf16x8*)(Wt_lo + gbo);
        }
        __syncthreads();
        #pragma unroll
        for (int kk = 0; kk < 2; ++kk) {
            const int cb = kk * 64 + (lane >> 4) * 16;  // col byte of frag
            bf16x8 ah[2], al[2], bh[2], bl[2];
            #pragma unroll
            for (int mi = 0; mi < 2; ++mi) {
                const int m = wr * 32 + mi * 16 + (lane & 15);
                ah[mi] = *(const bf16x8*)((char*)sm.a_hi + swz128(m, cb));
                al[mi] = *(const bf16x8*)((char*)sm.a_lo + swz128(m, cb));
            }
            #pragma unroll
            for (int ni = 0; ni < 2; ++ni) {
                const int n = wc * 32 + ni * 16 + (lane & 15);
                bh[ni] = *(const bf16x8*)((char*)sm.b_hi + swz128(n, cb));
                bl[ni] = *(const bf16x8*)((char*)sm.b_lo + swz128(n, cb));
            }
            #pragma unroll
            for (int mi = 0; mi < 2; ++mi)
                #pragma unroll
                for (int ni = 0; ni < 2; ++ni) {
                    f32x4 a = acc[mi][ni];
                    a = __builtin_amdgcn_mfma_f32_16x16x32_bf16(ah[mi], bh[ni], a, 0, 0, 0);
                    a = __builtin_amdgcn_mfma_f32_16x16x32_bf16(ah[mi], bl[ni], a, 0, 0, 0);
                    a = __builtin_amdgcn_mfma_f32_16x16x32_bf16(al[mi], bh[ni], a, 0, 0, 0);
                    acc[mi][ni] = a;
                }
        }
    }
    const int rr = (lane >> 4) * 4, colb = lane & 15;
    #pragma unroll
    for (int mi = 0; mi < 2; ++mi)
        #pragma unroll
        for (int ni = 0; ni < 2; ++ni) {
            bf16x4 hv, lv;
            #pragma unroll
            for (int r = 0; r < 4; ++r) {
                const BfPair p = split_bf16(acc[mi][ni][r]);
                const size_t idx =
                    (size_t)(ti * 64 + wr * 32 + mi * 16 + rr + r) * 1024 +
                    tj * 64 + wc * 32 + ni * 16 + colb;
                Q_hi[idx] = p.hi;
                Q_lo[idx] = p.lo;
                hv[r] = p.hi;
                lv[r] = p.lo;
            }
            if (ti != tj) {
                const size_t midx =
                    (size_t)(tj * 64 + wc * 32 + ni * 16 + colb) * 1024 +
                    ti * 64 + wr * 32 + mi * 16 + rr;
                *(bf16x4*)(Q_hi + midx) = hv;
                *(bf16x4*)(Q_lo + midx) = lv;
            }
        }
}

// ---- tiled split-bf16 NT GEMM, split-K x2 (R12/R16-verified) --------------
template <int CONV>
__global__ __launch_bounds__(256) void gemm_nt_kernel(
    const __bf16* __restrict__ Ah, const __bf16* __restrict__ Al,
    const __bf16* __restrict__ Bh, const __bf16* __restrict__ Bl,
    float* __restrict__ C0, float* __restrict__ C1,
    const float* __restrict__ Wsrc, __bf16* __restrict__ Wd_hi,
    __bf16* __restrict__ Wd_lo)
{
    __shared__ QSmem sm;
    if (CONV && blockIdx.x >= 128) {
        const int b = blockIdx.x - 128;             // 0..255
        const size_t base = (size_t)b * 4096 + (threadIdx.x << 2);
        #pragma unroll
        for (int q = 0; q < 4; ++q) {
            const size_t idx = base + (size_t)q * 1024;
            const f32x4 v = *(const f32x4*)(Wsrc + idx);
            bf16x4 hv, lv;
            #pragma unroll
            for (int j = 0; j < 4; ++j) {
                const BfPair p = split_bf16(v[j]);
                hv[j] = p.hi;
                lv[j] = p.lo;
            }
            *(bf16x4*)(Wd_hi + idx) = hv;
            *(bf16x4*)(Wd_lo + idx) = lv;
        }
        return;
    }

    const int kh   = blockIdx.x & 1;
    const int task = blockIdx.x >> 1;
    const int mt   = task >> 4;                 // 0..3   (64-row panel)
    const int nt   = task & 15;                 // 0..15  (64-col panel)
    const int t = threadIdx.x;
    const int lane = t & 63, w = t >> 6;        // 4 waves
    const int wr = w >> 1, wc = w & 1;          // wave's 32x32 sub-tile
    const int sr  = t >> 2;                     // row 0..63
    const int scb = (t & 3) * 16;               // col byte {0,16,32,48}
    const size_t ga = (size_t)(mt * 64 + sr) * 1024 + kh * 512 + scb / 2;
    const size_t gb = (size_t)(nt * 64 + sr) * 1024 + kh * 512 + scb / 2;

    f32x4 acc[2][2] = {};
    for (int k0 = 0; k0 < 512; k0 += 64) {
        if (k0) __syncthreads();                // prev step's reads done
        #pragma unroll
        for (int h = 0; h < 2; ++h) {
            const int cb = scb + h * 64;        // covers full 128-B row
            const size_t gao = ga + h * 32 + k0;
            const size_t gbo = gb + h * 32 + k0;
            *(bf16x8*)((char*)sm.a_hi + swz128(sr, cb)) = *(const bf16x8*)(Ah + gao);
            *(bf16x8*)((char*)sm.a_lo + swz128(sr, cb)) = *(const bf16x8*)(Al + gao);
            *(bf16x8*)((char*)sm.b_hi + swz128(sr, cb)) = *(const bf16x8*)(Bh + gbo);
            *(bf16x8*)((char*)sm.b_lo + swz128(sr, cb)) = *(const bf16x8*)(Bl + gbo);
        }
        __syncthreads();
        #pragma unroll
        for (int kk = 0; kk < 2; ++kk) {
            const int cb = kk * 64 + (lane >> 4) * 16;  // col byte of frag
            bf16x8 ah[2], al[2], bh[2], bl[2];
            #pragma unroll
            for (int mi = 0; mi < 2; ++mi) {
                const int m = wr * 32 + mi * 16 + (lane & 15);
                ah[mi] = *(const bf16x8*)((char*)sm.a_hi + swz128(m, cb));
                al[mi] = *(const bf16x8*)((char*)sm.a_lo + swz128(m, cb));
            }
            #pragma unroll
            for (int ni = 0; ni < 2; ++ni) {
                const int n = wc * 32 + ni * 16 + (lane & 15);
                bh[ni] = *(const bf16x8*)((char*)sm.b_hi + swz128(n, cb));
                bl[ni] = *(const bf16x8*)((char*)sm.b_lo + swz128(n, cb));
            }
            #pragma unroll
            for (int mi = 0; mi < 2; ++mi)
                #pragma unroll
                for (int ni = 0; ni < 2; ++ni) {
                    f32x4 a = acc[mi][ni];
                    a = __builtin_amdgcn_mfma_f32_16x16x32_bf16(ah[mi], bh[ni], a, 0, 0, 0);
                    a = __builtin_amdgcn_mfma_f32_16x16x32_bf16(ah[mi], bl[ni], a, 0, 0, 0);
                    a = __builtin_amdgcn_mfma_f32_16x16x32_bf16(al[mi], bh[ni], a, 0, 0, 0);
                    acc[mi][ni] = a;
                }
        }
    }
    float* Cc = kh ? C1 : C0;
    const int rr = (lane >> 4) * 4, colb = lane & 15;
    #pragma unroll
    for (int mi = 0; mi < 2; ++mi)
        #pragma unroll
        for (int ni = 0; ni < 2; ++ni)
            #pragma unroll
            for (int r = 0; r < 4; ++r)
                Cc[(size_t)(mt * 64 + wr * 32 + mi * 16 + rr + r) * 1024 +
                   nt * 64 + wc * 32 + ni * 16 + colb] = acc[mi][ni][r];
}

// ---------------- final squash: sums split-K chat, emits out ---------------
__global__ __launch_bounds__(256) void squash_out_kernel(
    const float* __restrict__ chat0, const float* __restrict__ chat1,
    float* __restrict__ outp)
{
    __shared__ float wsum[4];
    const int c = blockIdx.x, t = threadIdx.x;
    const int lane = t & 63, w = t >> 6;
    const size_t o = (size_t)c * 1024 + t * 4;
    f32x4 v = *(const f32x4*)(chat0 + o) + *(const f32x4*)(chat1 + o);
    float ss = v[0]*v[0] + v[1]*v[1] + v[2]*v[2] + v[3]*v[3];
    #pragma unroll
    for (int off = 32; off; off >>= 1) ss += __shfl_xor(ss, off, 64);
    if (lane == 0) wsum[w] = ss;
    __syncthreads();
    const float norm = wsum[0] + wsum[1] + wsum[2] + wsum[3];
    const float scale = norm / ((1.f + norm) * sqrtf(norm) + 1e-30f);
    *(f32x4*)(outp + o) = v * scale;
}

// ---------------- fallback: R3's proven monolithic fp32 kernel --------------
__global__ __launch_bounds__(512) void fallback_kernel(
    const float* __restrict__ enc, const float* __restrict__ W,
    float* __restrict__ outp)
{
    __shared__ float u_s[1024], s_s[1024], c_s[1024], chat_s[1024];
    __shared__ float b_s[64], d_s[64], red_s[8];
    const int t = threadIdx.x, lane = t & 63, w = t >> 6;
    const float* erow = enc + (size_t)blockIdx.x * 65536;

    if (t < 64) b_s[t] = 0.f;
    __syncthreads();

    for (int it = 0; it < 3; ++it) {
        if (it > 0) {
            f32x4 uf[4];
            #pragma unroll
            for (int q = 0; q < 2; ++q) {
                uf[2*q]   = *(const f32x4*)&u_s[q*512 + lane*8];
                uf[2*q+1] = *(const f32x4*)&u_s[q*512 + lane*8 + 4];
            }
            for (int r = 0; r < 8; ++r) {
                const int k = w * 8 + r;
                const float* ek = erow + (size_t)k * 1024;
                float sum = 0.f;
                #pragma unroll
                for (int q = 0; q < 2; ++q) {
                    f32x4 e0 = *(const f32x4*)(ek + q*512 + lane*8);
                    f32x4 e1 = *(const f32x4*)(ek + q*512 + lane*8 + 4);
                    #pragma unroll
                    for (int j = 0; j < 4; ++j) {
                        sum += e0[j] * uf[2*q][j];
                        sum += e1[j] * uf[2*q+1][j];
                    }
                }
                #pragma unroll
                for (int off = 32; off; off >>= 1) sum += __shfl_xor(sum, off, 64);
                if (lane == 0) b_s[k] += sum;
            }
            __syncthreads();
        }
        if (t < 64) {
            float bv = b_s[t], m = bv;
            #pragma unroll
            for (int off = 32; off; off >>= 1) m = fmaxf(m, __shfl_xor(m, off, 64));
            float e = expf(bv - m), sm = e;
            #pragma unroll
            for (int off = 32; off; off >>= 1) sm += __shfl_xor(sm, off, 64);
            d_s[t] = e / sm;
        }
        __syncthreads();
        {
            const int h0 = t * 2;
            float a0 = 0.f, a1 = 0.f;
            for (int k = 0; k < 64; ++k) {
                f32x2 ev = *(const f32x2*)(erow + (size_t)k * 1024 + h0);
                a0 += d_s[k] * ev[0]; a1 += d_s[k] * ev[1];
            }
            s_s[h0] = a0; s_s[h0+1] = a1;
        }
        __syncthreads();
        {
            f32x4 sf[4];
            #pragma unroll
            for (int q = 0; q < 2; ++q) {
                sf[2*q]   = *(const f32x4*)&s_s[q*512 + lane*8];
                sf[2*q+1] = *(const f32x4*)&s_s[q*512 + lane*8 + 4];
            }
            for (int r = 0; r < 128; ++r) {
                const int d = w * 128 + r;
                const float* wr = W + (size_t)d * 1024;
                float sum = 0.f;
                #pragma unroll
                for (int q = 0; q < 2; ++q) {
                    f32x4 w0 = *(const f32x4*)(wr + q*512 + lane*8);
                    f32x4 w1 = *(const f32x4*)(wr + q*512 + lane*8 + 4);
                    #pragma unroll
                    for (int j = 0; j < 4; ++j) {
                        sum += w0[j] * sf[2*q][j];
                        sum += w1[j] * sf[2*q+1][j];
                    }
                }
                #pragma unroll
                for (int off = 32; off; off >>= 1) sum += __shfl_xor(sum, off, 64);
                if (lane == 0) chat_s[d] = sum;
            }
        }
        __syncthreads();
        {
            const int h0 = t * 2;
            float v0 = chat_s[h0], v1 = chat_s[h0+1];
            float ss = v0*v0 + v1*v1;
            #pragma unroll
            for (int off = 32; off; off >>= 1) ss += __shfl_xor(ss, off, 64);
            if (lane == 0) red_s[w] = ss;
            __syncthreads();
            float norm = 0.f;
            #pragma unroll
            for (int i = 0; i < 8; ++i) norm += red_s[i];
            const float scale = norm / ((1.f + norm) * sqrtf(norm) + 1e-30f);
            c_s[h0] = v0 * scale; c_s[h0+1] = v1 * scale;
        }
        __syncthreads();
        if (it < 2) {
            const int h0 = t * 2;
            float uu0 = 0.f, uu1 = 0.f;
            for (int d = 0; d < 1024; ++d) {
                f32x2 wv = *(const f32x2*)(W + (size_t)d * 1024 + h0);
                uu0 += c_s[d] * wv[0]; uu1 += c_s[d] * wv[1];
            }
            u_s[h0] = uu0; u_s[h0+1] = uu1;
        } else {
            const int h0 = t * 2;
            f32x2 ov; ov[0] = c_s[h0]; ov[1] = c_s[h0+1];
            *(f32x2*)(outp + (size_t)blockIdx.x * 1024 + h0) = ov;
        }
        __syncthreads();
    }
}

extern "C" void kernel_launch(void* const* d_in, const int* in_sizes, int n_in,
                              void* d_out, int out_size, void* d_ws, size_t ws_size,
                              hipStream_t stream)
{
    const float* enc = (const float*)d_in[0];   // [256,64,1024] fp32
    const float* W   = (const float*)d_in[1];   // [1024,1024]   fp32
    float* outp = (float*)d_out;                // [256,1024]    fp32
    (void)in_sizes; (void)n_in; (void)out_size;

    // ws layout (11.5 MB)
    char* ws = (char*)d_ws;
    float*  b     = (float*) (ws + 0x000000);  //  64 KB [256,64]
    __bf16* s_hi  = (__bf16*)(ws + 0x080000);  // 512 KB [256,1024]
    __bf16* s_lo  = (__bf16*)(ws + 0x100000);  // 512 KB
    float*  y0    = (float*) (ws + 0x180000);  //   1 MB (y / chat, split-K lo)
    float*  y1    = (float*) (ws + 0x280000);  //   1 MB (y / chat, split-K hi)
    __bf16* Wx_hi = (__bf16*)(ws + 0x380000);  //   2 MB  Wt then Wb (reuse)
    __bf16* Wx_lo = (__bf16*)(ws + 0x580000);  //   2 MB
    __bf16* Q_hi  = (__bf16*)(ws + 0x780000);  //   2 MB [1024,1024]
    __bf16* Q_lo  = (__bf16*)(ws + 0x980000);  //   2 MB

    if (ws_size < 0xB80000) {
        fallback_kernel<<<256, 512, 0, stream>>>(enc, W, outp);
        return;
    }

    // A: convert_wt (blocks 0..255) || routing iter0 (blocks 256..511)
    routing_kernel<0, 1><<<512, 1024, 0, stream>>>(
        enc, y0, y1, b, s_hi, s_lo, W, Wx_hi, Wx_lo);

    // B: Q = Wt Wt^T (136 triangular tiles, mirror-written)
    gemm_q_kernel<<<136, 256, 0, stream>>>(Wx_hi, Wx_lo, Q_hi, Q_lo);

    // C: y = Q s (tiled)  || convert W -> Wb into the (now dead) Wt buffer
    gemm_nt_kernel<1><<<384, 256, 0, stream>>>(
        s_hi, s_lo, Q_hi, Q_lo, y0, y1, W, Wx_hi, Wx_lo);

    // D: routing iter1 (norm = s.y -> scale; b = scale*(E.y); new s)
    routing_kernel<1, 0><<<256, 1024, 0, stream>>>(
        enc, y0, y1, b, s_hi, s_lo, nullptr, nullptr, nullptr);

    // E: y = Q s (tiled)
    gemm_nt_kernel<0><<<128, 256, 0, stream>>>(
        s_hi, s_lo, Q_hi, Q_lo, y0, y1, nullptr, nullptr, nullptr);

    // F: routing iter2 (b += scale*(E.y); final s)
    routing_kernel<2, 0><<<256, 1024, 0, stream>>>(
        enc, y0, y1, b, s_hi, s_lo, nullptr, nullptr, nullptr);

    // G: chat = W s (tiled, B = Wb in Wx)
    gemm_nt_kernel<0><<<128, 256, 0, stream>>>(
        s_hi, s_lo, Wx_hi, Wx_lo, y0, y1, nullptr, nullptr, nullptr);

    // H: out = squash(chat)
    squash_out_kernel<<<256, 256, 0, stream>>>(y0, y1, outp);
}